// Round 6
// baseline (531.896 us; speedup 1.0000x reference)
//
#include <hip/hip_runtime.h>
#include <math.h>
#include <stdint.h>

#define BATCH 32
#define DIN   2048
#define DK    128
#define NREPS 400000
#define ACT   7
#define NGRP2 3125               /* groups of 128 rows, exact: 400000/128 */
#define GBLK  782                /* 3128 waves: one 128-row group per wave */

__device__ __forceinline__ void topk_insert(float s, int n,
    float& d0, float& d1, float& d2, float& d3, float& d4,
    int& i0, int& i1, int& i2, int& i3, int& i4)
{
    if (s < d4) {
        if (s < d3) {
            d4 = d3; i4 = i3;
            if (s < d2) {
                d3 = d2; i3 = i2;
                if (s < d1) {
                    d2 = d1; i2 = i1;
                    if (s < d0) { d1 = d0; i1 = i0; d0 = s; i0 = n; }
                    else        { d1 = s;  i1 = n; }
                } else { d2 = s; i2 = n; }
            } else { d3 = s; i3 = n; }
        } else { d4 = s; i4 = n; }
    }
}

// async 16-B global->LDS (per-lane global src, wave-uniform LDS base + lane*16)
__device__ __forceinline__ void gload_lds16(const float* g, float* l)
{
    __builtin_amdgcn_global_load_lds(
        (const __attribute__((address_space(1))) void*)g,
        (__attribute__((address_space(3))) void*)l, 16, 0, 0);
}

// ---------------------------------------------------------------------------
// Kernel 1: batch_rep = x @ W_enc + b_enc. Writes brep_t[k][b] = -2*br[b][k]
// (k-major, pre-scaled) and brnorm[b] = ||br_b||^2.
// ---------------------------------------------------------------------------
__global__ __launch_bounds__(256) void encoder_kernel(
    const float* __restrict__ x, const float* __restrict__ W,
    const float* __restrict__ be, float* __restrict__ brept,
    float* __restrict__ brnorm)
{
    __shared__ float xs[DIN];
    __shared__ float part[256];
    __shared__ float vrow[DK];
    const int b = blockIdx.x, t = threadIdx.x;

    const float4* x4 = (const float4*)(x + (size_t)b * DIN);
    float4* xs4 = (float4*)xs;
    xs4[t]       = x4[t];
    xs4[t + 256] = x4[t + 256];
    __syncthreads();

    const int d = t & 127, hh = t >> 7;
    const float* Wp = W + (size_t)(hh * 1024) * DK + d;
    const float* xp = xs + hh * 1024;
    float a0 = 0.f, a1 = 0.f, a2 = 0.f, a3 = 0.f;
    for (int i = 0; i < 1024; i += 8) {
        const float w0 = Wp[(size_t)i * DK];
        const float w1 = Wp[(size_t)(i + 1) * DK];
        const float w2 = Wp[(size_t)(i + 2) * DK];
        const float w3 = Wp[(size_t)(i + 3) * DK];
        const float w4 = Wp[(size_t)(i + 4) * DK];
        const float w5 = Wp[(size_t)(i + 5) * DK];
        const float w6 = Wp[(size_t)(i + 6) * DK];
        const float w7 = Wp[(size_t)(i + 7) * DK];
        a0 = fmaf(xp[i],     w0, a0);
        a1 = fmaf(xp[i + 1], w1, a1);
        a2 = fmaf(xp[i + 2], w2, a2);
        a3 = fmaf(xp[i + 3], w3, a3);
        a0 = fmaf(xp[i + 4], w4, a0);
        a1 = fmaf(xp[i + 5], w5, a1);
        a2 = fmaf(xp[i + 6], w6, a2);
        a3 = fmaf(xp[i + 7], w7, a3);
    }
    part[t] = (a0 + a1) + (a2 + a3);
    __syncthreads();
    if (t < DK) {
        float v = part[t] + part[t + 128] + be[t];
        brept[t * BATCH + b] = -2.0f * v;
        vrow[t] = v * v;
    }
    __syncthreads();
    if (t == 0) {
        float s = 0.f;
        for (int i = 0; i < DK; i++) s += vrow[i];
        brnorm[b] = s;
    }
}

// ---------------------------------------------------------------------------
// Kernel 2: lane-per-2-rows streaming distance + per-wave top-5.
// R3-R5 lesson: all register-staging variants land at 242us because only ~2
// line-misses/wave are in flight (compiler sinks loads to point-of-use;
// 93 cyc/line latency-bound). Fix: async global_load_lds staging of each
// wave's 128 rows into a per-wave LDS double buffer (8 instrs = 64 lines in
// flight per fill, zero VGPR cost), counted vmcnt(8) so the next buffer's
// loads stay in flight while computing the current one. K in 8 chunks of 16;
// FMA k-order identical to the verified kernel -> bit-identical outputs.
// b-operand: brt in LDS, broadcast ds_read_b128 (unchanged from R3-R5).
// Stage buffer layout [q][lane]x4f matches the HW's linear lane*16 dest and
// is the uniform min-bank pattern (conflict-free). The wave's stage buffer is
// reused as its top-k scatter slab (stride 36) after the final vmcnt(0).
// ---------------------------------------------------------------------------
#define FMA4(Acc, S) \
    Acc.x = fmaf(p0.x, S.x, Acc.x); Acc.x = fmaf(p1.x, S.y, Acc.x); \
    Acc.x = fmaf(p2.x, S.z, Acc.x); Acc.x = fmaf(p3.x, S.w, Acc.x); \
    Acc.y = fmaf(p0.y, S.x, Acc.y); Acc.y = fmaf(p1.y, S.y, Acc.y); \
    Acc.y = fmaf(p2.y, S.z, Acc.y); Acc.y = fmaf(p3.y, S.w, Acc.y); \
    Acc.z = fmaf(p0.z, S.x, Acc.z); Acc.z = fmaf(p1.z, S.y, Acc.z); \
    Acc.z = fmaf(p2.z, S.z, Acc.z); Acc.z = fmaf(p3.z, S.w, Acc.z); \
    Acc.w = fmaf(p0.w, S.x, Acc.w); Acc.w = fmaf(p1.w, S.y, Acc.w); \
    Acc.w = fmaf(p2.w, S.z, Acc.w); Acc.w = fmaf(p3.w, S.w, Acc.w);

// issue one 16-k chunk (h) of both row-sets into buffer bsel (8 instrs)
#define STAGE(h, bsel) do {                                         \
    float* dst_ = swave + (bsel) * 2048;                            \
    const float* s0p_ = rbase0 + (h) * 16;                          \
    const float* s1p_ = rbase1 + (h) * 16;                          \
    gload_lds16(s0p_ + 0,  dst_ + 0 * 256);                         \
    gload_lds16(s0p_ + 4,  dst_ + 1 * 256);                         \
    gload_lds16(s0p_ + 8,  dst_ + 2 * 256);                         \
    gload_lds16(s0p_ + 12, dst_ + 3 * 256);                         \
    gload_lds16(s1p_ + 0,  dst_ + 4 * 256);                         \
    gload_lds16(s1p_ + 4,  dst_ + 5 * 256);                         \
    gload_lds16(s1p_ + 8,  dst_ + 6 * 256);                         \
    gload_lds16(s1p_ + 12, dst_ + 7 * 256);                         \
} while (0)

__global__ __launch_bounds__(256, 2) void dist_topk_kernel(
    const float* __restrict__ reps, const float* __restrict__ brt,
    float* __restrict__ pd, int* __restrict__ pi)
{
    __shared__ float sbrt[DK * BATCH];     // 16 KB, [k][b]
    __shared__ float stage[4][4096];       // 64 KB: per-wave 2x8KB dbuf / slab
    const int t = threadIdx.x, blk = blockIdx.x;
    const int wid = t >> 6, ln = t & 63;
    const int b = ln & 31, h2 = ln >> 5;
    float* swave = stage[wid];

    {   // stage brt -> LDS, coalesced float4 (4096 floats / 256 threads)
        const float4* bsrc = (const float4*)brt;
        float4* bdst = (float4*)sbrt;
        #pragma unroll
        for (int i = 0; i < 4; i++) bdst[t + 256 * i] = bsrc[t + 256 * i];
    }
    __syncthreads();

    float d0 = 3.0e38f, d1 = 3.0e38f, d2 = 3.0e38f, d3 = 3.0e38f, d4 = 3.0e38f;
    int   i0 = 0, i1 = 0, i2 = 0, i3 = 0, i4 = 0;

    const float4* sb4 = (const float4*)sbrt;
    const int g = blk * 4 + wid;           // one group per wave, static

    if (g < NGRP2) {
        const float* rbase0 = reps + (size_t)(g * 128 + ln) * DK;
        const float* rbase1 = rbase0 + 64 * DK;

        float4 a0[8], a1[8];
        #pragma unroll
        for (int q = 0; q < 8; q++) {
            a0[q] = make_float4(0.f, 0.f, 0.f, 0.f);
            a1[q] = make_float4(0.f, 0.f, 0.f, 0.f);
        }
        float n0 = 0.f, n1 = 0.f;

        STAGE(0, 0);
        #pragma unroll 1
        for (int h = 0; h < 8; h++) {
            if (h < 7) {
                STAGE(h + 1, (h + 1) & 1);
                asm volatile("s_waitcnt vmcnt(8)" ::: "memory");
            } else {
                asm volatile("s_waitcnt vmcnt(0)" ::: "memory");
            }
            __builtin_amdgcn_sched_barrier(0);

            const float* buf = swave + (h & 1) * 2048;
            #pragma unroll
            for (int q = 0; q < 4; q++) {
                const float4 s0 = *(const float4*)&buf[q * 256 + ln * 4];
                const float4 s1 = *(const float4*)&buf[(4 + q) * 256 + ln * 4];
                n0 = fmaf(s0.x, s0.x, n0); n0 = fmaf(s0.y, s0.y, n0);
                n0 = fmaf(s0.z, s0.z, n0); n0 = fmaf(s0.w, s0.w, n0);
                n1 = fmaf(s1.x, s1.x, n1); n1 = fmaf(s1.y, s1.y, n1);
                n1 = fmaf(s1.z, s1.z, n1); n1 = fmaf(s1.w, s1.w, n1);
                const float4* pb = sb4 + (h * 16 + q * 4) * 8;   // k-row base
                #pragma unroll
                for (int j = 0; j < 8; j++) {
                    const float4 p0 = pb[j], p1 = pb[j + 8], p2 = pb[j + 16], p3 = pb[j + 24];
                    float4 A = a0[j];
                    FMA4(A, s0)
                    a0[j] = A;
                    float4 B = a1[j];
                    FMA4(B, s1)
                    a1[j] = B;
                }
            }
        }

        // ---- stage buffer now free (vmcnt(0) drained): reuse as scatter slab
        float* wd = swave;                 // 64 x 36 floats, stride 36
        // pass 0: rows g*128 + 0..63
        #pragma unroll
        for (int q = 0; q < 8; q++) {
            float4 v = a0[q];
            v.x += n0; v.y += n0; v.z += n0; v.w += n0;
            *(float4*)&wd[ln * 36 + 4 * q] = v;
        }
        asm volatile("s_waitcnt lgkmcnt(0)" ::: "memory");
        {
            const int nb = g * 128;
            #pragma unroll 4
            for (int s = 0; s < 32; s++) {
                const int row = h2 * 32 + s;
                topk_insert(wd[row * 36 + b], nb + row, d0, d1, d2, d3, d4, i0, i1, i2, i3, i4);
            }
        }
        asm volatile("s_waitcnt lgkmcnt(0)" ::: "memory");

        // pass 1: rows g*128 + 64..127
        #pragma unroll
        for (int q = 0; q < 8; q++) {
            float4 v = a1[q];
            v.x += n1; v.y += n1; v.z += n1; v.w += n1;
            *(float4*)&wd[ln * 36 + 4 * q] = v;
        }
        asm volatile("s_waitcnt lgkmcnt(0)" ::: "memory");
        {
            const int nb = g * 128 + 64;
            #pragma unroll 4
            for (int s = 0; s < 32; s++) {
                const int row = h2 * 32 + s;
                topk_insert(wd[row * 36 + b], nb + row, d0, d1, d2, d3, d4, i0, i1, i2, i3, i4);
            }
        }
        asm volatile("s_waitcnt lgkmcnt(0)" ::: "memory");
    }

    // ---- block merge: 8 lists (4 waves x 2 halves) per batch row.
    // sbrt is no longer needed -> reuse as block-shared merge scratch.
    __syncthreads();
    float* cD = sbrt;                  // 256*5 = 1280 f
    int*   cI = (int*)(sbrt + 1280);   // 1280 i
    {
        const int base = t * 5;
        cD[base]     = d0; cI[base]     = i0;
        cD[base + 1] = d1; cI[base + 1] = i1;
        cD[base + 2] = d2; cI[base + 2] = i2;
        cD[base + 3] = d3; cI[base + 3] = i3;
        cD[base + 4] = d4; cI[base + 4] = i4;
    }
    __syncthreads();
    if (t < 32) {
        float e0 = 3.0e38f, e1 = 3.0e38f, e2 = 3.0e38f, e3 = 3.0e38f, e4 = 3.0e38f;
        int   j0 = 0, j1 = 0, j2 = 0, j3 = 0, j4 = 0;
        for (int j = 0; j < 8; j++) {
            const int base = (t + 32 * j) * 5;
            #pragma unroll
            for (int e = 0; e < 5; e++)
                topk_insert(cD[base + e], cI[base + e],
                            e0, e1, e2, e3, e4, j0, j1, j2, j3, j4);
        }
        const int ob = (blk * BATCH + t) * 5;
        pd[ob] = e0; pd[ob + 1] = e1; pd[ob + 2] = e2; pd[ob + 3] = e3; pd[ob + 4] = e4;
        pi[ob] = j0; pi[ob + 1] = j1; pi[ob + 2] = j2; pi[ob + 3] = j3; pi[ob + 4] = j4;
    }
}

// ---------------------------------------------------------------------------
// Kernel 3: merge G partial lists per b, softmax(-dist), gather actions.
// ---------------------------------------------------------------------------
__global__ __launch_bounds__(256) void final_kernel(
    const float* __restrict__ pd, const int* __restrict__ pi,
    const float* __restrict__ brnorm, const float* __restrict__ actions,
    float* __restrict__ out, int G)
{
    __shared__ float lD[256 * 5];
    __shared__ int   lI[256 * 5];
    __shared__ float sD[32 * 5];
    __shared__ int   sI[32 * 5];
    const int b = blockIdx.x, t = threadIdx.x;

    float d0 = 3.0e38f, d1 = 3.0e38f, d2 = 3.0e38f, d3 = 3.0e38f, d4 = 3.0e38f;
    int   i0 = 0, i1 = 0, i2 = 0, i3 = 0, i4 = 0;
    for (int g = t; g < G; g += 256) {
        const int base = (g * BATCH + b) * 5;
        #pragma unroll
        for (int e = 0; e < 5; e++)
            topk_insert(pd[base + e], pi[base + e],
                        d0, d1, d2, d3, d4, i0, i1, i2, i3, i4);
    }
    lD[t * 5] = d0; lD[t * 5 + 1] = d1; lD[t * 5 + 2] = d2; lD[t * 5 + 3] = d3; lD[t * 5 + 4] = d4;
    lI[t * 5] = i0; lI[t * 5 + 1] = i1; lI[t * 5 + 2] = i2; lI[t * 5 + 3] = i3; lI[t * 5 + 4] = i4;
    __syncthreads();
    if (t < 32) {
        d0 = d1 = d2 = d3 = d4 = 3.0e38f; i0 = i1 = i2 = i3 = i4 = 0;
        for (int s = 0; s < 8; s++) {
            const int base = (t * 8 + s) * 5;
            #pragma unroll
            for (int e = 0; e < 5; e++)
                topk_insert(lD[base + e], lI[base + e],
                            d0, d1, d2, d3, d4, i0, i1, i2, i3, i4);
        }
        sD[t * 5] = d0; sD[t * 5 + 1] = d1; sD[t * 5 + 2] = d2; sD[t * 5 + 3] = d3; sD[t * 5 + 4] = d4;
        sI[t * 5] = i0; sI[t * 5 + 1] = i1; sI[t * 5 + 2] = i2; sI[t * 5 + 3] = i3; sI[t * 5 + 4] = i4;
    }
    __syncthreads();
    if (t == 0) {
        d0 = d1 = d2 = d3 = d4 = 3.0e38f; i0 = i1 = i2 = i3 = i4 = 0;
        for (int s = 0; s < 32; s++) {
            const int base = s * 5;
            #pragma unroll
            for (int e = 0; e < 5; e++)
                topk_insert(sD[base + e], sI[base + e],
                            d0, d1, d2, d3, d4, i0, i1, i2, i3, i4);
        }
        const float bn = brnorm[b];
        float dist[5]; int idx[5];
        dist[0] = d0; dist[1] = d1; dist[2] = d2; dist[3] = d3; dist[4] = d4;
        idx[0] = i0; idx[1] = i1; idx[2] = i2; idx[3] = i3; idx[4] = i4;
        float dmin = 3.0e38f;
        #pragma unroll
        for (int e = 0; e < 5; e++) {
            dist[e] = sqrtf(fmaxf(dist[e] + bn, 1e-12f));
            dmin = fminf(dmin, dist[e]);
        }
        float w[5], wsum = 0.f;
        #pragma unroll
        for (int e = 0; e < 5; e++) { w[e] = expf(dmin - dist[e]); wsum += w[e]; }
        const float inv = 1.0f / wsum;
        for (int a = 0; a < ACT; a++) {
            float o = 0.f;
            #pragma unroll
            for (int e = 0; e < 5; e++)
                o = fmaf(w[e], actions[(size_t)idx[e] * ACT + a], o);
            out[b * ACT + a] = o * inv;
        }
    }
}

extern "C" void kernel_launch(void* const* d_in, const int* in_sizes, int n_in,
                              void* d_out, int out_size, void* d_ws, size_t ws_size,
                              hipStream_t stream)
{
    (void)in_sizes; (void)n_in; (void)out_size;
    const float* x       = (const float*)d_in[0];
    const float* W       = (const float*)d_in[1];
    const float* be      = (const float*)d_in[2];
    const float* reps    = (const float*)d_in[3];
    const float* actions = (const float*)d_in[4];
    // d_in[5] = k (always 5; structural)

    float* ws     = (float*)d_ws;
    float* brept  = ws;            // 4096 floats (brep_t[k][b], pre-scaled -2)
    float* brnorm = ws + 4096;     // 32 floats
    float* pd     = ws + 4160;     // G*32*5 floats

    int G = GBLK;                  // 782: one 128-row group per wave
    {
        const size_t avail_f = ws_size / 4;
        if (avail_f < 4160 + (size_t)G * 320) {
            long fit = ((long)avail_f - 4160) / 320;
            G = (fit < 1) ? 1 : (int)fit;
            if (G > GBLK) G = GBLK;
        }
    }
    int* pi = (int*)(pd + (size_t)G * BATCH * 5);

    encoder_kernel  <<<32, 256, 0, stream>>>(x, W, be, brept, brnorm);
    dist_topk_kernel<<<G,  256, 0, stream>>>(reps, brept, pd, pi);
    final_kernel    <<<32, 256, 0, stream>>>(pd, pi, brnorm, actions, (float*)d_out, G);
}

// Round 7
// 510.995 us; speedup vs baseline: 1.0409x; 1.0409x over previous
//
#include <hip/hip_runtime.h>
#include <math.h>

#define BATCH 32
#define DIN   2048
#define DK    128
#define NREPS 400000
#define ACT   7
#define NGRP  (NREPS / 64)   /* 6250 groups of 64 rows, exact */
#define GBLK  1563           /* 6252 waves: ~1 group per wave, 4 blocks/CU resident */

__device__ __forceinline__ void topk_insert(float s, int n,
    float& d0, float& d1, float& d2, float& d3, float& d4,
    int& i0, int& i1, int& i2, int& i3, int& i4)
{
    if (s < d4) {
        if (s < d3) {
            d4 = d3; i4 = i3;
            if (s < d2) {
                d3 = d2; i3 = i2;
                if (s < d1) {
                    d2 = d1; i2 = i1;
                    if (s < d0) { d1 = d0; i1 = i0; d0 = s; i0 = n; }
                    else        { d1 = s;  i1 = n; }
                } else { d2 = s; i2 = n; }
            } else { d3 = s; i3 = n; }
        } else { d4 = s; i4 = n; }
    }
}

// ---------------------------------------------------------------------------
// Kernel 1: batch_rep = x @ W_enc + b_enc. Writes brep_t[k][b] = -2*br[b][k]
// (k-major, pre-scaled) and brnorm[b] = ||br_b||^2.
// ---------------------------------------------------------------------------
__global__ __launch_bounds__(256) void encoder_kernel(
    const float* __restrict__ x, const float* __restrict__ W,
    const float* __restrict__ be, float* __restrict__ brept,
    float* __restrict__ brnorm)
{
    __shared__ float xs[DIN];
    __shared__ float part[256];
    __shared__ float vrow[DK];
    const int b = blockIdx.x, t = threadIdx.x;

    const float4* x4 = (const float4*)(x + (size_t)b * DIN);
    float4* xs4 = (float4*)xs;
    xs4[t]       = x4[t];
    xs4[t + 256] = x4[t + 256];
    __syncthreads();

    const int d = t & 127, hh = t >> 7;
    const float* Wp = W + (size_t)(hh * 1024) * DK + d;
    const float* xp = xs + hh * 1024;
    float a0 = 0.f, a1 = 0.f, a2 = 0.f, a3 = 0.f;
    for (int i = 0; i < 1024; i += 8) {
        const float w0 = Wp[(size_t)i * DK];
        const float w1 = Wp[(size_t)(i + 1) * DK];
        const float w2 = Wp[(size_t)(i + 2) * DK];
        const float w3 = Wp[(size_t)(i + 3) * DK];
        const float w4 = Wp[(size_t)(i + 4) * DK];
        const float w5 = Wp[(size_t)(i + 5) * DK];
        const float w6 = Wp[(size_t)(i + 6) * DK];
        const float w7 = Wp[(size_t)(i + 7) * DK];
        a0 = fmaf(xp[i],     w0, a0);
        a1 = fmaf(xp[i + 1], w1, a1);
        a2 = fmaf(xp[i + 2], w2, a2);
        a3 = fmaf(xp[i + 3], w3, a3);
        a0 = fmaf(xp[i + 4], w4, a0);
        a1 = fmaf(xp[i + 5], w5, a1);
        a2 = fmaf(xp[i + 6], w6, a2);
        a3 = fmaf(xp[i + 7], w7, a3);
    }
    part[t] = (a0 + a1) + (a2 + a3);
    __syncthreads();
    if (t < DK) {
        float v = part[t] + part[t + 128] + be[t];
        brept[t * BATCH + b] = -2.0f * v;
        vrow[t] = v * v;
    }
    __syncthreads();
    if (t == 0) {
        float s = 0.f;
        for (int i = 0; i < DK; i++) s += vrow[i];
        brnorm[b] = s;
    }
}

// ---------------------------------------------------------------------------
// Kernel 2: lane-per-row streaming distance + per-wave top-5.
// EXACT R0 (207us) structure: lane owns one 64-row-group row; streams 128
// floats as 8xfloat4 per 32-k superchunk (full cache lines); acc[32] (one
// per batch row); br operand wave-uniform (scalar/L1-cached); per-wave LDS
// stride-36 slab for the dist transpose; no __syncthreads in hot loop.
// SOLE change vs R0: grid 782 -> 1563 blocks. R0's 782 blocks = 3.05/CU
// could never fill the 4-blocks/CU LDS-residency limit (occupancy 26%).
// R3-R6 showed dur x occupancy ~ const (latency-bound; only TLP helps):
// 6252 waves -> sustained ~4 blocks/CU with queue refill. Stride loop
// (g += 4*G) keeps any workspace-shrunken G correct.
// ---------------------------------------------------------------------------
__global__ __launch_bounds__(256, 4) void dist_topk_kernel(
    const float* __restrict__ reps, const float* __restrict__ brt,
    float* __restrict__ pd, int* __restrict__ pi, int nwaves)
{
    __shared__ float wdist[4 * 64 * 36];   // 36 KB, per-wave slabs
    const int t = threadIdx.x, g = blockIdx.x;
    const int wid = t >> 6, ln = t & 63;
    const int b = ln & 31, h = ln >> 5;
    float* wd = wdist + wid * (64 * 36);

    float d0 = 3.0e38f, d1 = 3.0e38f, d2 = 3.0e38f, d3 = 3.0e38f, d4 = 3.0e38f;
    int   i0 = 0, i1 = 0, i2 = 0, i3 = 0, i4 = 0;

    for (int grp = g * 4 + wid; grp < NGRP; grp += nwaves) {
        const float4* rp = (const float4*)(reps + (size_t)(grp * 64 + ln) * DK);
        float acc[32];
        #pragma unroll
        for (int i = 0; i < 32; i++) acc[i] = 0.f;
        float nrm = 0.f;

        #pragma unroll 1
        for (int c = 0; c < 4; c++) {          // 4 superchunks of 32 k
            float4 r[8];
            #pragma unroll
            for (int q = 0; q < 8; q++) r[q] = rp[c * 8 + q];
            const float* bp0 = brt + c * 32 * BATCH;
            #pragma unroll
            for (int q = 0; q < 8; q++) {
                const float4 rr = r[q];
                nrm = fmaf(rr.x, rr.x, nrm);
                nrm = fmaf(rr.y, rr.y, nrm);
                nrm = fmaf(rr.z, rr.z, nrm);
                nrm = fmaf(rr.w, rr.w, nrm);
                const float* bp = bp0 + q * 4 * BATCH;
                #pragma unroll
                for (int bb = 0; bb < 32; bb++) {
                    float a = acc[bb];
                    a = fmaf(bp[bb],             rr.x, a);
                    a = fmaf(bp[BATCH + bb],     rr.y, a);
                    a = fmaf(bp[2 * BATCH + bb], rr.z, a);
                    a = fmaf(bp[3 * BATCH + bb], rr.w, a);
                    acc[bb] = a;
                }
            }
        }

        // scatter this lane's 32 dists (one per batch row) to the wave slab
        #pragma unroll
        for (int q = 0; q < 8; q++) {
            float4 v;
            v.x = acc[4 * q]     + nrm;
            v.y = acc[4 * q + 1] + nrm;
            v.z = acc[4 * q + 2] + nrm;
            v.w = acc[4 * q + 3] + nrm;
            *(float4*)&wd[ln * 36 + 4 * q] = v;
        }
        asm volatile("s_waitcnt lgkmcnt(0)" ::: "memory");

        // lane (b,h) scans 32 rows of its half, inserts into register top-5
        const int nb = grp * 64;
        #pragma unroll 4
        for (int s = 0; s < 32; s++) {
            const int row = h * 32 + s;
            const float dv = wd[row * 36 + b];
            topk_insert(dv, nb + row, d0, d1, d2, d3, d4, i0, i1, i2, i3, i4);
        }
        asm volatile("s_waitcnt lgkmcnt(0)" ::: "memory");
    }

    // ---- block merge: 8 lists (4 waves x 2 halves) per batch row
    __syncthreads();
    float* cD = wdist;                 // 256*5 = 1280 f
    int*   cI = (int*)(wdist + 1280);  // 1280 i
    {
        const int base = t * 5;
        cD[base]     = d0; cI[base]     = i0;
        cD[base + 1] = d1; cI[base + 1] = i1;
        cD[base + 2] = d2; cI[base + 2] = i2;
        cD[base + 3] = d3; cI[base + 3] = i3;
        cD[base + 4] = d4; cI[base + 4] = i4;
    }
    __syncthreads();
    if (t < 32) {
        float e0 = 3.0e38f, e1 = 3.0e38f, e2 = 3.0e38f, e3 = 3.0e38f, e4 = 3.0e38f;
        int   j0 = 0, j1 = 0, j2 = 0, j3 = 0, j4 = 0;
        for (int j = 0; j < 8; j++) {
            const int base = (t + 32 * j) * 5;
            #pragma unroll
            for (int e = 0; e < 5; e++)
                topk_insert(cD[base + e], cI[base + e],
                            e0, e1, e2, e3, e4, j0, j1, j2, j3, j4);
        }
        const int ob = (g * BATCH + t) * 5;
        pd[ob] = e0; pd[ob + 1] = e1; pd[ob + 2] = e2; pd[ob + 3] = e3; pd[ob + 4] = e4;
        pi[ob] = j0; pi[ob + 1] = j1; pi[ob + 2] = j2; pi[ob + 3] = j3; pi[ob + 4] = j4;
    }
}

// ---------------------------------------------------------------------------
// Kernel 3: merge G partial lists per b, softmax(-dist), gather actions.
// ---------------------------------------------------------------------------
__global__ __launch_bounds__(256) void final_kernel(
    const float* __restrict__ pd, const int* __restrict__ pi,
    const float* __restrict__ brnorm, const float* __restrict__ actions,
    float* __restrict__ out, int G)
{
    __shared__ float lD[256 * 5];
    __shared__ int   lI[256 * 5];
    __shared__ float sD[32 * 5];
    __shared__ int   sI[32 * 5];
    const int b = blockIdx.x, t = threadIdx.x;

    float d0 = 3.0e38f, d1 = 3.0e38f, d2 = 3.0e38f, d3 = 3.0e38f, d4 = 3.0e38f;
    int   i0 = 0, i1 = 0, i2 = 0, i3 = 0, i4 = 0;
    for (int g = t; g < G; g += 256) {
        const int base = (g * BATCH + b) * 5;
        #pragma unroll
        for (int e = 0; e < 5; e++)
            topk_insert(pd[base + e], pi[base + e],
                        d0, d1, d2, d3, d4, i0, i1, i2, i3, i4);
    }
    lD[t * 5] = d0; lD[t * 5 + 1] = d1; lD[t * 5 + 2] = d2; lD[t * 5 + 3] = d3; lD[t * 5 + 4] = d4;
    lI[t * 5] = i0; lI[t * 5 + 1] = i1; lI[t * 5 + 2] = i2; lI[t * 5 + 3] = i3; lI[t * 5 + 4] = i4;
    __syncthreads();
    if (t < 32) {
        d0 = d1 = d2 = d3 = d4 = 3.0e38f; i0 = i1 = i2 = i3 = i4 = 0;
        for (int s = 0; s < 8; s++) {
            const int base = (t * 8 + s) * 5;
            #pragma unroll
            for (int e = 0; e < 5; e++)
                topk_insert(lD[base + e], lI[base + e],
                            d0, d1, d2, d3, d4, i0, i1, i2, i3, i4);
        }
        sD[t * 5] = d0; sD[t * 5 + 1] = d1; sD[t * 5 + 2] = d2; sD[t * 5 + 3] = d3; sD[t * 5 + 4] = d4;
        sI[t * 5] = i0; sI[t * 5 + 1] = i1; sI[t * 5 + 2] = i2; sI[t * 5 + 3] = i3; sI[t * 5 + 4] = i4;
    }
    __syncthreads();
    if (t == 0) {
        d0 = d1 = d2 = d3 = d4 = 3.0e38f; i0 = i1 = i2 = i3 = i4 = 0;
        for (int s = 0; s < 32; s++) {
            const int base = s * 5;
            #pragma unroll
            for (int e = 0; e < 5; e++)
                topk_insert(sD[base + e], sI[base + e],
                            d0, d1, d2, d3, d4, i0, i1, i2, i3, i4);
        }
        const float bn = brnorm[b];
        float dist[5]; int idx[5];
        dist[0] = d0; dist[1] = d1; dist[2] = d2; dist[3] = d3; dist[4] = d4;
        idx[0] = i0; idx[1] = i1; idx[2] = i2; idx[3] = i3; idx[4] = i4;
        float dmin = 3.0e38f;
        #pragma unroll
        for (int e = 0; e < 5; e++) {
            dist[e] = sqrtf(fmaxf(dist[e] + bn, 1e-12f));
            dmin = fminf(dmin, dist[e]);
        }
        float w[5], wsum = 0.f;
        #pragma unroll
        for (int e = 0; e < 5; e++) { w[e] = expf(dmin - dist[e]); wsum += w[e]; }
        const float inv = 1.0f / wsum;
        for (int a = 0; a < ACT; a++) {
            float o = 0.f;
            #pragma unroll
            for (int e = 0; e < 5; e++)
                o = fmaf(w[e], actions[(size_t)idx[e] * ACT + a], o);
            out[b * ACT + a] = o * inv;
        }
    }
}

extern "C" void kernel_launch(void* const* d_in, const int* in_sizes, int n_in,
                              void* d_out, int out_size, void* d_ws, size_t ws_size,
                              hipStream_t stream)
{
    (void)in_sizes; (void)n_in; (void)out_size;
    const float* x       = (const float*)d_in[0];
    const float* W       = (const float*)d_in[1];
    const float* be      = (const float*)d_in[2];
    const float* reps    = (const float*)d_in[3];
    const float* actions = (const float*)d_in[4];
    // d_in[5] = k (always 5; structural)

    float* ws     = (float*)d_ws;
    float* brept  = ws;            // 4096 floats (brep_t[k][b], pre-scaled -2)
    float* brnorm = ws + 4096;     // 32 floats
    float* pd     = ws + 4160;     // G*32*5 floats

    int G = GBLK;                  // 1563: ~1 group/wave, 4 blocks/CU resident
    {
        const size_t avail_f = ws_size / 4;
        if (avail_f < 4160 + (size_t)G * 320) {
            long fit = ((long)avail_f - 4160) / 320;
            G = (fit < 1) ? 1 : (int)fit;
            if (G > GBLK) G = GBLK;
        }
    }
    int* pi = (int*)(pd + (size_t)G * BATCH * 5);
    const int nwaves = G * 4;

    encoder_kernel  <<<32, 256, 0, stream>>>(x, W, be, brept, brnorm);
    dist_topk_kernel<<<G,  256, 0, stream>>>(reps, brept, pd, pi, nwaves);
    final_kernel    <<<32, 256, 0, stream>>>(pd, pi, brnorm, actions, (float*)d_out, G);
}

// Round 8
// 510.614 us; speedup vs baseline: 1.0417x; 1.0007x over previous
//
#include <hip/hip_runtime.h>
#include <math.h>

#define BATCH 32
#define DIN   2048
#define DK    128
#define NREPS 400000
#define ACT   7
#define NGRP  (NREPS / 64)   /* 6250 groups of 64 rows, exact */
#define GBLK  1563           /* 6252 waves: ~1 group per wave */

/* constant-address-space alias of a runtime buffer: the memory is invariant
   during the dispatch (written by the PRIOR kernel), and all offsets are
   wave-uniform -> the compiler emits s_load (SMEM pipe, K$-cached) instead
   of VMEM. This takes the 4096 uniform b-operand fetches per group off the
   TA/L1 pipe, which R0/R7's counters identify as the saturated resource
   (~100K VMEM instr/CU x ~4-5cyc = the entire 210us; VALU 15% idle,
   occupancy-insensitive). */
typedef __attribute__((address_space(4))) const float kcfloat;

__device__ __forceinline__ void topk_insert(float s, int n,
    float& d0, float& d1, float& d2, float& d3, float& d4,
    int& i0, int& i1, int& i2, int& i3, int& i4)
{
    if (s < d4) {
        if (s < d3) {
            d4 = d3; i4 = i3;
            if (s < d2) {
                d3 = d2; i3 = i2;
                if (s < d1) {
                    d2 = d1; i2 = i1;
                    if (s < d0) { d1 = d0; i1 = i0; d0 = s; i0 = n; }
                    else        { d1 = s;  i1 = n; }
                } else { d2 = s; i2 = n; }
            } else { d3 = s; i3 = n; }
        } else { d4 = s; i4 = n; }
    }
}

// ---------------------------------------------------------------------------
// Kernel 1: batch_rep = x @ W_enc + b_enc. Writes brep_t[k][b] = -2*br[b][k]
// (k-major, pre-scaled) and brnorm[b] = ||br_b||^2.
// ---------------------------------------------------------------------------
__global__ __launch_bounds__(256) void encoder_kernel(
    const float* __restrict__ x, const float* __restrict__ W,
    const float* __restrict__ be, float* __restrict__ brept,
    float* __restrict__ brnorm)
{
    __shared__ float xs[DIN];
    __shared__ float part[256];
    __shared__ float vrow[DK];
    const int b = blockIdx.x, t = threadIdx.x;

    const float4* x4 = (const float4*)(x + (size_t)b * DIN);
    float4* xs4 = (float4*)xs;
    xs4[t]       = x4[t];
    xs4[t + 256] = x4[t + 256];
    __syncthreads();

    const int d = t & 127, hh = t >> 7;
    const float* Wp = W + (size_t)(hh * 1024) * DK + d;
    const float* xp = xs + hh * 1024;
    float a0 = 0.f, a1 = 0.f, a2 = 0.f, a3 = 0.f;
    for (int i = 0; i < 1024; i += 8) {
        const float w0 = Wp[(size_t)i * DK];
        const float w1 = Wp[(size_t)(i + 1) * DK];
        const float w2 = Wp[(size_t)(i + 2) * DK];
        const float w3 = Wp[(size_t)(i + 3) * DK];
        const float w4 = Wp[(size_t)(i + 4) * DK];
        const float w5 = Wp[(size_t)(i + 5) * DK];
        const float w6 = Wp[(size_t)(i + 6) * DK];
        const float w7 = Wp[(size_t)(i + 7) * DK];
        a0 = fmaf(xp[i],     w0, a0);
        a1 = fmaf(xp[i + 1], w1, a1);
        a2 = fmaf(xp[i + 2], w2, a2);
        a3 = fmaf(xp[i + 3], w3, a3);
        a0 = fmaf(xp[i + 4], w4, a0);
        a1 = fmaf(xp[i + 5], w5, a1);
        a2 = fmaf(xp[i + 6], w6, a2);
        a3 = fmaf(xp[i + 7], w7, a3);
    }
    part[t] = (a0 + a1) + (a2 + a3);
    __syncthreads();
    if (t < DK) {
        float v = part[t] + part[t + 128] + be[t];
        brept[t * BATCH + b] = -2.0f * v;
        vrow[t] = v * v;
    }
    __syncthreads();
    if (t == 0) {
        float s = 0.f;
        for (int i = 0; i < DK; i++) s += vrow[i];
        brnorm[b] = s;
    }
}

// ---------------------------------------------------------------------------
// Kernel 2: lane-per-row streaming distance + per-wave top-5.
// EXACT R7 structure (R0's verified 207us kernel + 1563-block grid). SOLE
// change: the wave-uniform b-operand reads go through an address_space(4)
// pointer so they issue as s_load on the scalar pipe (SGPR operand of
// v_fmac), off the saturated TA/L1 pipe. FMA order unchanged ->
// bit-identical distances and top-k.
// ---------------------------------------------------------------------------
__global__ __launch_bounds__(256, 4) void dist_topk_kernel(
    const float* __restrict__ reps, const float* __restrict__ brt,
    float* __restrict__ pd, int* __restrict__ pi, int nwaves)
{
    __shared__ float wdist[4 * 64 * 36];   // 36 KB, per-wave slabs
    const int t = threadIdx.x, g = blockIdx.x;
    const int wid = t >> 6, ln = t & 63;
    const int b = ln & 31, h = ln >> 5;
    float* wd = wdist + wid * (64 * 36);

    const kcfloat* brtc = (const kcfloat*)brt;

    float d0 = 3.0e38f, d1 = 3.0e38f, d2 = 3.0e38f, d3 = 3.0e38f, d4 = 3.0e38f;
    int   i0 = 0, i1 = 0, i2 = 0, i3 = 0, i4 = 0;

    for (int grp = g * 4 + wid; grp < NGRP; grp += nwaves) {
        const float4* rp = (const float4*)(reps + (size_t)(grp * 64 + ln) * DK);
        float acc[32];
        #pragma unroll
        for (int i = 0; i < 32; i++) acc[i] = 0.f;
        float nrm = 0.f;

        #pragma unroll 1
        for (int c = 0; c < 4; c++) {          // 4 superchunks of 32 k
            float4 r[8];
            #pragma unroll
            for (int q = 0; q < 8; q++) r[q] = rp[c * 8 + q];
            const kcfloat* bp0 = brtc + c * 32 * BATCH;
            #pragma unroll
            for (int q = 0; q < 8; q++) {
                const float4 rr = r[q];
                nrm = fmaf(rr.x, rr.x, nrm);
                nrm = fmaf(rr.y, rr.y, nrm);
                nrm = fmaf(rr.z, rr.z, nrm);
                nrm = fmaf(rr.w, rr.w, nrm);
                const kcfloat* bp = bp0 + q * 4 * BATCH;
                #pragma unroll
                for (int bb = 0; bb < 32; bb++) {
                    float a = acc[bb];
                    a = fmaf(bp[bb],             rr.x, a);
                    a = fmaf(bp[BATCH + bb],     rr.y, a);
                    a = fmaf(bp[2 * BATCH + bb], rr.z, a);
                    a = fmaf(bp[3 * BATCH + bb], rr.w, a);
                    acc[bb] = a;
                }
            }
        }

        // scatter this lane's 32 dists (one per batch row) to the wave slab
        #pragma unroll
        for (int q = 0; q < 8; q++) {
            float4 v;
            v.x = acc[4 * q]     + nrm;
            v.y = acc[4 * q + 1] + nrm;
            v.z = acc[4 * q + 2] + nrm;
            v.w = acc[4 * q + 3] + nrm;
            *(float4*)&wd[ln * 36 + 4 * q] = v;
        }
        asm volatile("s_waitcnt lgkmcnt(0)" ::: "memory");

        // lane (b,h) scans 32 rows of its half, inserts into register top-5
        const int nb = grp * 64;
        #pragma unroll 4
        for (int s = 0; s < 32; s++) {
            const int row = h * 32 + s;
            const float dv = wd[row * 36 + b];
            topk_insert(dv, nb + row, d0, d1, d2, d3, d4, i0, i1, i2, i3, i4);
        }
        asm volatile("s_waitcnt lgkmcnt(0)" ::: "memory");
    }

    // ---- block merge: 8 lists (4 waves x 2 halves) per batch row
    __syncthreads();
    float* cD = wdist;                 // 256*5 = 1280 f
    int*   cI = (int*)(wdist + 1280);  // 1280 i
    {
        const int base = t * 5;
        cD[base]     = d0; cI[base]     = i0;
        cD[base + 1] = d1; cI[base + 1] = i1;
        cD[base + 2] = d2; cI[base + 2] = i2;
        cD[base + 3] = d3; cI[base + 3] = i3;
        cD[base + 4] = d4; cI[base + 4] = i4;
    }
    __syncthreads();
    if (t < 32) {
        float e0 = 3.0e38f, e1 = 3.0e38f, e2 = 3.0e38f, e3 = 3.0e38f, e4 = 3.0e38f;
        int   j0 = 0, j1 = 0, j2 = 0, j3 = 0, j4 = 0;
        for (int j = 0; j < 8; j++) {
            const int base = (t + 32 * j) * 5;
            #pragma unroll
            for (int e = 0; e < 5; e++)
                topk_insert(cD[base + e], cI[base + e],
                            e0, e1, e2, e3, e4, j0, j1, j2, j3, j4);
        }
        const int ob = (g * BATCH + t) * 5;
        pd[ob] = e0; pd[ob + 1] = e1; pd[ob + 2] = e2; pd[ob + 3] = e3; pd[ob + 4] = e4;
        pi[ob] = j0; pi[ob + 1] = j1; pi[ob + 2] = j2; pi[ob + 3] = j3; pi[ob + 4] = j4;
    }
}

// ---------------------------------------------------------------------------
// Kernel 3: merge G partial lists per b, softmax(-dist), gather actions.
// ---------------------------------------------------------------------------
__global__ __launch_bounds__(256) void final_kernel(
    const float* __restrict__ pd, const int* __restrict__ pi,
    const float* __restrict__ brnorm, const float* __restrict__ actions,
    float* __restrict__ out, int G)
{
    __shared__ float lD[256 * 5];
    __shared__ int   lI[256 * 5];
    __shared__ float sD[32 * 5];
    __shared__ int   sI[32 * 5];
    const int b = blockIdx.x, t = threadIdx.x;

    float d0 = 3.0e38f, d1 = 3.0e38f, d2 = 3.0e38f, d3 = 3.0e38f, d4 = 3.0e38f;
    int   i0 = 0, i1 = 0, i2 = 0, i3 = 0, i4 = 0;
    for (int g = t; g < G; g += 256) {
        const int base = (g * BATCH + b) * 5;
        #pragma unroll
        for (int e = 0; e < 5; e++)
            topk_insert(pd[base + e], pi[base + e],
                        d0, d1, d2, d3, d4, i0, i1, i2, i3, i4);
    }
    lD[t * 5] = d0; lD[t * 5 + 1] = d1; lD[t * 5 + 2] = d2; lD[t * 5 + 3] = d3; lD[t * 5 + 4] = d4;
    lI[t * 5] = i0; lI[t * 5 + 1] = i1; lI[t * 5 + 2] = i2; lI[t * 5 + 3] = i3; lI[t * 5 + 4] = i4;
    __syncthreads();
    if (t < 32) {
        d0 = d1 = d2 = d3 = d4 = 3.0e38f; i0 = i1 = i2 = i3 = i4 = 0;
        for (int s = 0; s < 8; s++) {
            const int base = (t * 8 + s) * 5;
            #pragma unroll
            for (int e = 0; e < 5; e++)
                topk_insert(lD[base + e], lI[base + e],
                            d0, d1, d2, d3, d4, i0, i1, i2, i3, i4);
        }
        sD[t * 5] = d0; sD[t * 5 + 1] = d1; sD[t * 5 + 2] = d2; sD[t * 5 + 3] = d3; sD[t * 5 + 4] = d4;
        sI[t * 5] = i0; sI[t * 5 + 1] = i1; sI[t * 5 + 2] = i2; sI[t * 5 + 3] = i3; sI[t * 5 + 4] = i4;
    }
    __syncthreads();
    if (t == 0) {
        d0 = d1 = d2 = d3 = d4 = 3.0e38f; i0 = i1 = i2 = i3 = i4 = 0;
        for (int s = 0; s < 32; s++) {
            const int base = s * 5;
            #pragma unroll
            for (int e = 0; e < 5; e++)
                topk_insert(sD[base + e], sI[base + e],
                            d0, d1, d2, d3, d4, i0, i1, i2, i3, i4);
        }
        const float bn = brnorm[b];
        float dist[5]; int idx[5];
        dist[0] = d0; dist[1] = d1; dist[2] = d2; dist[3] = d3; dist[4] = d4;
        idx[0] = i0; idx[1] = i1; idx[2] = i2; idx[3] = i3; idx[4] = i4;
        float dmin = 3.0e38f;
        #pragma unroll
        for (int e = 0; e < 5; e++) {
            dist[e] = sqrtf(fmaxf(dist[e] + bn, 1e-12f));
            dmin = fminf(dmin, dist[e]);
        }
        float w[5], wsum = 0.f;
        #pragma unroll
        for (int e = 0; e < 5; e++) { w[e] = expf(dmin - dist[e]); wsum += w[e]; }
        const float inv = 1.0f / wsum;
        for (int a = 0; a < ACT; a++) {
            float o = 0.f;
            #pragma unroll
            for (int e = 0; e < 5; e++)
                o = fmaf(w[e], actions[(size_t)idx[e] * ACT + a], o);
            out[b * ACT + a] = o * inv;
        }
    }
}

extern "C" void kernel_launch(void* const* d_in, const int* in_sizes, int n_in,
                              void* d_out, int out_size, void* d_ws, size_t ws_size,
                              hipStream_t stream)
{
    (void)in_sizes; (void)n_in; (void)out_size;
    const float* x       = (const float*)d_in[0];
    const float* W       = (const float*)d_in[1];
    const float* be      = (const float*)d_in[2];
    const float* reps    = (const float*)d_in[3];
    const float* actions = (const float*)d_in[4];
    // d_in[5] = k (always 5; structural)

    float* ws     = (float*)d_ws;
    float* brept  = ws;            // 4096 floats (brep_t[k][b], pre-scaled -2)
    float* brnorm = ws + 4096;     // 32 floats
    float* pd     = ws + 4160;     // G*32*5 floats

    int G = GBLK;                  // 1563: ~1 group/wave
    {
        const size_t avail_f = ws_size / 4;
        if (avail_f < 4160 + (size_t)G * 320) {
            long fit = ((long)avail_f - 4160) / 320;
            G = (fit < 1) ? 1 : (int)fit;
            if (G > GBLK) G = GBLK;
        }
    }
    int* pi = (int*)(pd + (size_t)G * BATCH * 5);
    const int nwaves = G * 4;

    encoder_kernel  <<<32, 256, 0, stream>>>(x, W, be, brept, brnorm);
    dist_topk_kernel<<<G,  256, 0, stream>>>(reps, brept, pd, pi, nwaves);
    final_kernel    <<<32, 256, 0, stream>>>(pd, pi, brnorm, actions, (float*)d_out, G);
}